// Round 18
// baseline (10200.170 us; speedup 1.0000x reference)
//
#include <hip/hip_runtime.h>

// ---------------------------------------------------------------------------
// ADRNN persistent R18 = R17 with the identified WAR race FIXED:
// the h0/h2 consumer counters were MERGED across two stages, letting the
// writer's own staging adds mask the lagging consumer stage (stage1 lags by
// design: its hg0 blocks also compute rout; same for stage3/tout). At lag
// j=k-3 the writer's slot k&3 == reader's slot (j-1)&3 -> corruption.
// Fix: split WAR counters per consumer group: RDA(c)=same-stage readers,
// RDB(c)=downstream-stage readers (c=0: stage1; c=2: stage3); writers poll
// BOTH >= 8*(k-2), bounding each group to >= k-2 (slots then never collide).
// All else identical to R17 (R16 c-in-registers + 4-deep per-edge dataflow).
// ---------------------------------------------------------------------------

typedef _Float16 half_t;
typedef _Float16 half8 __attribute__((ext_vector_type(8)));
typedef float floatx4 __attribute__((ext_vector_type(4)));
typedef unsigned long long ull_t;

// half-unit offsets inside d_ws
#define OFF_W0 0        // r_Wih0 padded  [2048][64]
#define OFF_W1 131072   // r_Whh0         [2048][512]
#define OFF_W2 1179648  // r_Wih1         [2048][512]
#define OFF_W3 2228224  // r_Whh1         [2048][512]
#define OFF_W4 3276800  // t_Wih0 cols0-48 padded [2048][64]
#define OFF_W5 3407872  // t_Wih0 cols49-95 padded [2048][64]
#define OFF_W6 3538944  // t_Whh0         [2048][512]
#define OFF_W7 4587520  // t_Wih1         [2048][512]
#define OFF_W8 5636096  // t_Whh1         [2048][512]
#define OFF_W9 6684672  // Wr padded      [48][512]
#define OFF_W10 6709248 // Wt padded      [16][512]
#define W_TOTAL 6717440
#define H_BASE  6717440              // h[4 cells][4 slots][128][512] halves
#define RO_BASE 7766016              // ro16[4 slots][128][64] halves
#define HALF_TOTAL 7798784
// byte offsets (c lives in registers)
#define STATE_BYTE_OFF (H_BASE * 2)          // 13434880
#define BAR_BYTE_OFF (HALF_TOTAL * 2)        // 15597568 (16 KiB counters)
#define X16_BYTE_OFF (BAR_BYTE_OFF + 16384)  // 15613952
#define WS_NEED_X16 ((unsigned long long)X16_BYTE_OFF + 8388608ull) // 24002560
#define STATE_BYTES (X16_BYTE_OFF - STATE_BYTE_OFF)

#define NBLK 256
#define TOUT_BASE (128 * 512 * 47)

__device__ __forceinline__ floatx4 mfma16(half8 a, half8 b, floatx4 c) {
  return __builtin_amdgcn_mfma_f32_16x16x32_f16(a, b, c, 0, 0, 0);
}
__device__ __forceinline__ float fast_sig(float x) {
  x = fminf(fmaxf(x, -30.f), 30.f);
  float e = __expf(-x);
  return __builtin_amdgcn_rcpf(1.f + e);
}
__device__ __forceinline__ float fast_tanh(float x) {
  x = fminf(fmaxf(x, -15.f), 15.f);
  float e = __expf(-2.f * x);
  return (1.f - e) * __builtin_amdgcn_rcpf(1.f + e);
}

// LLC-coherent 16B burst loads
template <int N>
__device__ __forceinline__ void burst_g(half8 (&bb)[N], const half_t* p) {
#pragma unroll
  for (int ks = 0; ks < N; ++ks)
    asm volatile("global_load_dwordx4 %0, %1, off sc0 sc1"
                 : "=v"(bb[ks]) : "v"(p + ks * 32));
}
__device__ __forceinline__ void drain_vm() {
  asm volatile("s_waitcnt vmcnt(0)" ::: "memory");
  __builtin_amdgcn_sched_barrier(0);
}
__device__ __forceinline__ void store_h4_coh(half_t* p, ull_t v) {
  __hip_atomic_store((ull_t*)p, v, __ATOMIC_RELAXED, __HIP_MEMORY_SCOPE_AGENT);
}
// poll monotonic LLC counter until >= target
__device__ __forceinline__ void poll_llc(const unsigned* p, unsigned target) {
  for (;;) {
    unsigned v;
    asm volatile("global_load_dword %0, %1, off sc0 sc1\ns_waitcnt vmcnt(0)"
                 : "=v"(v) : "v"(p));
    if (v >= target) return;
    __builtin_amdgcn_s_sleep(1);
  }
}
__device__ __forceinline__ void cnt_add(unsigned* p) {
  (void)__hip_atomic_fetch_add(p, 1u, __ATOMIC_RELAXED,
                               __HIP_MEMORY_SCOPE_AGENT);
}

// Cooperative slab staging: 16 rows x 512 halves (16KB) -> LDS, XOR-swizzled.
__device__ __forceinline__ void slab_issue(half8 (&tmp)[4],
                                           const half_t* __restrict__ src,
                                           int tid) {
#pragma unroll
  for (int j = 0; j < 4; ++j) {
    const int u = tid + j * 256;
    asm volatile("global_load_dwordx4 %0, %1, off sc0 sc1"
                 : "=v"(tmp[j]) : "v"(src + (u >> 6) * 512 + (u & 63) * 8));
  }
}
__device__ __forceinline__ void slab_write(char* base, const half8 (&tmp)[4],
                                           int tid) {
#pragma unroll
  for (int j = 0; j < 4; ++j) {
    const int u = tid + j * 256;
    const int row = u >> 6, seg = u & 63;
    *(half8*)(base + row * 1024 + ((seg * 16) ^ ((row & 7) << 4))) = tmp[j];
  }
}

// GEMM: B-frags from swizzled LDS slab, A (weights) streamed from L2.
// C/D: lane l -> col(batch)=l15, rows(gate hcols)=q*4+r.
template <int NT, int NSEG, int LDW>
__device__ __forceinline__ void gemm_lb(const half_t* __restrict__ W,
                                        const int* wrow, const char* ldsb,
                                        int lk, int q, int l15,
                                        floatx4 (&acc)[NT]) {
  const int bbase = l15 * 1024;
  const int bxor = (l15 & 7) << 4;
#pragma unroll
  for (int ks = 0; ks < NSEG; ++ks) {
    const int kb = ks * 32 + lk;
    half8 b = *(const half8*)(ldsb + bbase + ((q * 16 + ks * 64) ^ bxor));
#pragma unroll
    for (int n = 0; n < NT; ++n) {
      half8 a = *(const half8*)(W + (long)(wrow[n] + l15) * LDW + kb);
      acc[n] = mfma16(a, b, acc[n]);
    }
  }
}
// GEMM with register B-frags (RO in t0).
template <int NT, int NSEG, int LDW>
__device__ __forceinline__ void gemm_regB(const half_t* __restrict__ W,
                                          const int* wrow,
                                          const half8 (&bb)[NSEG], int lk,
                                          int l15, floatx4 (&acc)[NT]) {
#pragma unroll
  for (int ks = 0; ks < NSEG; ++ks) {
    const int kb = ks * 32 + lk;
#pragma unroll
    for (int n = 0; n < NT; ++n) {
      half8 a = *(const half8*)(W + (long)(wrow[n] + l15) * LDW + kb);
      acc[n] = mfma16(a, bb[ks], acc[n]);
    }
  }
}
// K=64 X gemm with plain cached B loads from x16.
__device__ __forceinline__ void gemm_x16(const half_t* __restrict__ W,
                                         const int* wrow,
                                         const half_t* __restrict__ xb, int lk,
                                         int l15, floatx4 (&acc)[4]) {
#pragma unroll
  for (int ks = 0; ks < 2; ++ks) {
    const int kb = ks * 32 + lk;
    half8 b = *(const half8*)(xb + kb);
#pragma unroll
    for (int n = 0; n < 4; ++n) {
      half8 a = *(const half8*)(W + (long)(wrow[n] + l15) * 64 + kb);
      acc[n] = mfma16(a, b, acc[n]);
    }
  }
}
// Fallback X gemm from fp32 inputs.
__device__ __forceinline__ void gemm_xf(const float* __restrict__ xr,
                                        const float* __restrict__ xt, int t,
                                        int batch, const half_t* __restrict__ W,
                                        const int* wrow, int lk, int l15,
                                        floatx4 (&acc)[4]) {
#pragma unroll
  for (int ks = 0; ks < 2; ++ks) {
    const int kb = ks * 32 + lk;
    half8 b;
    const long base = (long)batch * 512 + t;
#pragma unroll
    for (int j = 0; j < 8; ++j) {
      const int kk = kb + j;
      float f = 0.f;
      if (kk < 47) f = xr[base * 47 + kk];
      else if (kk < 49) f = xt[base * 2 + (kk - 47)];
      b[j] = (half_t)f;
    }
#pragma unroll
    for (int n = 0; n < 4; ++n) {
      half8 a = *(const half8*)(W + (long)(wrow[n] + l15) * 64 + kb);
      acc[n] = mfma16(a, b, acc[n]);
    }
  }
}

// LSTM epilogue with REGISTER c-state.
__device__ __forceinline__ void lstm_epi_reg(floatx4 (&acc)[4],
                                             const float* __restrict__ bias,
                                             floatx4& creg,
                                             half_t* __restrict__ hdst,
                                             int batch, int hcol0) {
  const floatx4 bI = *(const floatx4*)(bias + hcol0);
  const floatx4 bF = *(const floatx4*)(bias + 512 + hcol0);
  const floatx4 bG = *(const floatx4*)(bias + 1024 + hcol0);
  const floatx4 bO = *(const floatx4*)(bias + 1536 + hcol0);
  const int off = batch * 512 + hcol0;
  union { ull_t u; _Float16 h[4]; } pk;
#pragma unroll
  for (int r = 0; r < 4; ++r) {
    const float gi = acc[0][r] + bI[r];
    const float gf = acc[1][r] + bF[r];
    const float gg = acc[2][r] + bG[r];
    const float go = acc[3][r] + bO[r];
    creg[r] = fast_sig(gf) * creg[r] + fast_sig(gi) * fast_tanh(gg);
    pk.h[r] = (half_t)(fast_sig(go) * fast_tanh(creg[r]));
  }
  store_h4_coh(hdst + off, pk.u);
}

__global__ __launch_bounds__(256, 1) void adrnn_persist(
    const float* __restrict__ xr, const float* __restrict__ xt,
    const float* __restrict__ b_r0, const float* __restrict__ b_r1,
    const float* __restrict__ b_t0, const float* __restrict__ b_t1,
    const float* __restrict__ brv, const float* __restrict__ btv,
    half_t* __restrict__ w16, float* __restrict__ cbase,
    float* __restrict__ out, unsigned* bar, const half_t* __restrict__ x16,
    int use_x16) {
  __shared__ half8 lds_v[2048];  // 32KB: two 16KB swizzled B slabs
  char* lds0 = (char*)lds_v;
  char* lds1 = lds0 + 16384;

  const int bid = blockIdx.x;
  const int tid = threadIdx.x;
  const int lane = tid & 63;
  const int w = tid >> 6;
  const int l15 = lane & 15;
  const int q = lane >> 4;
  const int lk = q * 8;
  half_t* H = w16 + H_BASE;
  half_t* RO = w16 + RO_BASE;
#define HB(cell, s) (H + (((cell)*4 + (s)) << 16))

  // R11 decode: weights partitioned by (stage, hgHi) -> L2-resident per XCD
  const int stage = (bid & 7) >> 1;
  const int hgHi = bid & 1;
  const int rr = bid >> 3;        // 0..31
  const int hgLo = rr >> 3;       // 0..3
  const int bg = rr & 7;          // 0..7
  const int hg = hgHi * 4 + hgLo; // 0..7 (64 hcols each)
  const int c0w = hg * 64 + w * 16;
  const int b0 = bg * 16;
  const int batch = b0 + l15;
  const int hcol0 = c0w + q * 4;
  const int sd = (stage == 0) ? 0 : (stage == 1) ? 1 : (stage == 2) ? 3 : 4;
  int wrow[4] = {c0w, 512 + c0w, 1024 + c0w, 1536 + c0w};

  // per-edge monotonic counters (128B-separated lines)
#define WRH(c, b) (bar + ((c)*8 + (b)) * 32)          // producers of h[c]
#define RDA(c, b) (bar + 1024 + ((c)*8 + (b)) * 32)   // same-stage readers
#define RDB(c, b) (bar + 2048 + ((c)*8 + (b)) * 32)   // downstream readers
#define WRRO(b)   (bar + 3072 + (b)*32)
#define RDRO(b)   (bar + 3328 + (b)*32)

  floatx4 creg = {0.f, 0.f, 0.f, 0.f};  // persistent register c-state

  for (int k = 0; k < 517; ++k) {
    const int rs = (k - 1) & 3;   // read slot (k=0 -> slot 3, zeroed)
    const int wsl = k & 3;        // write slot
    const int t = k - sd;
    const bool valid = (t >= 0 && t < 512);
    const unsigned ku = (unsigned)k;

    // ---- dependency waits (tid0 polls; all targets <= tick k-1) ----
    if (tid == 0) {
      if (k > 0) {  // RAW: producers of tick k-1 done
        if (stage == 0) {
          poll_llc(WRH(0, bg), 8u * ku);
        } else if (stage == 1) {
          poll_llc(WRH(0, bg), 8u * ku);
          poll_llc(WRH(1, bg), 8u * ku);
        } else if (stage == 2) {
          poll_llc(WRH(2, bg), 8u * ku);
          poll_llc(WRRO(bg), ku);
        } else {
          poll_llc(WRH(2, bg), 8u * ku);
          poll_llc(WRH(3, bg), 8u * ku);
        }
      }
      if (k >= 3) {  // WAR: EACH consumer group of slot wsl's old data done
        const unsigned kw = ku - 2u;
        if (stage == 0) {
          poll_llc(RDA(0, bg), 8u * kw);   // self readers
          poll_llc(RDB(0, bg), 8u * kw);   // stage-1 readers (split fix)
        } else if (stage == 1) {
          poll_llc(RDA(1, bg), 8u * kw);
          if (hg == 0) poll_llc(RDRO(bg), 8u * kw);
        } else if (stage == 2) {
          poll_llc(RDA(2, bg), 8u * kw);   // self readers
          poll_llc(RDB(2, bg), 8u * kw);   // stage-3 readers (split fix)
        } else {
          poll_llc(RDA(3, bg), 8u * kw);
        }
      }
    }
    __syncthreads();

    // ---- staging: ALL cross-block reads happen here, then rd-signals ----
    half8 bro[2];
    {
      half8 s0[4], s1[4];
      if (stage == 0) {
        slab_issue(s0, HB(0, rs) + b0 * 512, tid);
        drain_vm();
        slab_write(lds0, s0, tid);
      } else if (stage == 1) {
        slab_issue(s0, HB(0, rs) + b0 * 512, tid);
        slab_issue(s1, HB(1, rs) + b0 * 512, tid);
        drain_vm();
        slab_write(lds0, s0, tid);
        slab_write(lds1, s1, tid);
      } else if (stage == 2) {
        slab_issue(s0, HB(2, rs) + b0 * 512, tid);
        burst_g<2>(bro, RO + rs * 8192 + batch * 64 + lk);  // RO staged
        drain_vm();
        slab_write(lds0, s0, tid);
      } else {
        slab_issue(s0, HB(2, rs) + b0 * 512, tid);
        slab_issue(s1, HB(3, rs) + b0 * 512, tid);
        drain_vm();
        slab_write(lds0, s0, tid);
        slab_write(lds1, s1, tid);
      }
    }
    __syncthreads();
    if (tid == 0) {  // rd signals: data fetched, slots may be overwritten
      if (stage == 0) cnt_add(RDA(0, bg));
      else if (stage == 1) { cnt_add(RDB(0, bg)); cnt_add(RDA(1, bg)); }
      else if (stage == 2) { cnt_add(RDA(2, bg)); cnt_add(RDRO(bg)); }
      else { cnt_add(RDB(2, bg)); cnt_add(RDA(3, bg)); }
    }

    // ---- main compute ----
    if (valid) {
      floatx4 acc[4] = {};
      if (stage == 0) {        // r0: X @ Wih0^T + h0 @ Whh0^T
        if (use_x16)
          gemm_x16(w16 + OFF_W0, wrow, x16 + (long)t * 8192 + batch * 64, lk, l15, acc);
        else
          gemm_xf(xr, xt, t, batch, w16 + OFF_W0, wrow, lk, l15, acc);
        gemm_lb<4, 16, 512>(w16 + OFF_W1, wrow, lds0, lk, q, l15, acc);
        lstm_epi_reg(acc, b_r0, creg, HB(0, wsl), batch, hcol0);
      } else if (stage == 1) { // r1
        gemm_lb<4, 16, 512>(w16 + OFF_W2, wrow, lds0, lk, q, l15, acc);
        gemm_lb<4, 16, 512>(w16 + OFF_W3, wrow, lds1, lk, q, l15, acc);
        lstm_epi_reg(acc, b_r1, creg, HB(1, wsl), batch, hcol0);
      } else if (stage == 2) { // t0: X + RO(staged regs) + h2
        if (use_x16)
          gemm_x16(w16 + OFF_W4, wrow, x16 + (long)t * 8192 + batch * 64, lk, l15, acc);
        else
          gemm_xf(xr, xt, t, batch, w16 + OFF_W4, wrow, lk, l15, acc);
        gemm_regB<4, 2, 64>(w16 + OFF_W5, wrow, bro, lk, l15, acc);
        gemm_lb<4, 16, 512>(w16 + OFF_W6, wrow, lds0, lk, q, l15, acc);
        lstm_epi_reg(acc, b_t0, creg, HB(2, wsl), batch, hcol0);
      } else {                 // t1
        gemm_lb<4, 16, 512>(w16 + OFF_W7, wrow, lds0, lk, q, l15, acc);
        gemm_lb<4, 16, 512>(w16 + OFF_W8, wrow, lds1, lk, q, l15, acc);
        lstm_epi_reg(acc, b_t1, creg, HB(3, wsl), batch, hcol0);
      }
    }

    // ---- rout in r1-hg0 blocks (reuses lds1 = h1(k-2) slab), waves 0..2 ----
    if (stage == 1 && hg == 0 && w < 3) {
      const int tro = k - 2;
      if (tro >= 0 && tro < 512) {
        int wr1[1] = {w * 16};
        floatx4 accr[1] = {};
        gemm_lb<1, 16, 512>(w16 + OFF_W9, wr1, lds1, lk, q, l15, accr);
        const int rb = b0 + l15;
        const int wc0 = w * 16 + q * 4;
        union { ull_t u2; _Float16 h[4]; } rp;
#pragma unroll
        for (int r = 0; r < 4; ++r) {
          const int wc = wc0 + r;
          float v = 0.f;
          if (wc < 47) {
            v = accr[0][r] + brv[wc];
            out[((long)rb * 512 + tro) * 47 + wc] = v;
          }
          rp.h[r] = (half_t)v;
        }
        store_h4_coh(RO + wsl * 8192 + rb * 64 + wc0, rp.u2);
      }
    }
    // ---- tout in t1-hg0 blocks (reuses lds1 = h3(k-5) slab), wave 0 ----
    if (stage == 3 && hg == 0 && w == 0) {
      const int tto = k - 5;
      if (tto >= 0 && tto < 512) {
        int wt1[1] = {0};
        floatx4 accw[1] = {};
        gemm_lb<1, 16, 512>(w16 + OFF_W10, wt1, lds1, lk, q, l15, accw);
        if (q == 0) {
          const int rb = b0 + l15;
#pragma unroll
          for (int r = 0; r < 2; ++r)
            out[TOUT_BASE + ((long)rb * 512 + tto) * 2 + r] = accw[0][r] + btv[r];
        }
      }
    }

    // ---- drain stores; signal production ----
    drain_vm();
    __syncthreads();
    if (tid == 0) {
      cnt_add(WRH(stage, bg));
      if (stage == 1 && hg == 0) cnt_add(WRRO(bg));
    }
  }
#undef HB
#undef WRH
#undef RDA
#undef RDB
#undef WRRO
#undef RDRO
}

// fp32 -> fp16 weight conversion into [n][k] layout with zero padding.
__global__ __launch_bounds__(256) void conv_w(
    const float* __restrict__ rWih0, const float* __restrict__ rWhh0,
    const float* __restrict__ rWih1, const float* __restrict__ rWhh1,
    const float* __restrict__ tWih0, const float* __restrict__ tWhh0,
    const float* __restrict__ tWih1, const float* __restrict__ tWhh1,
    const float* __restrict__ Wr, const float* __restrict__ Wt,
    half_t* __restrict__ w16) {
  const int idx = blockIdx.x * 256 + threadIdx.x;
  if (idx >= W_TOTAL) return;
  float v = 0.f;
  if (idx < OFF_W1) {
    int n = idx >> 6, kk = idx & 63;
    if (kk < 49) v = rWih0[n * 49 + kk];
  } else if (idx < OFF_W2) {
    int r = idx - OFF_W1; v = rWhh0[r];
  } else if (idx < OFF_W3) {
    int r = idx - OFF_W2; v = rWih1[r];
  } else if (idx < OFF_W4) {
    int r = idx - OFF_W3; v = rWhh1[r];
  } else if (idx < OFF_W5) {
    int r = idx - OFF_W4; int n = r >> 6, kk = r & 63;
    if (kk < 49) v = tWih0[n * 96 + kk];
  } else if (idx < OFF_W6) {
    int r = idx - OFF_W5; int n = r >> 6, kk = r & 63;
    if (kk < 47) v = tWih0[n * 96 + 49 + kk];
  } else if (idx < OFF_W7) {
    int r = idx - OFF_W6; v = tWhh0[r];
  } else if (idx < OFF_W8) {
    int r = idx - OFF_W7; v = tWih1[r];
  } else if (idx < OFF_W9) {
    int r = idx - OFF_W8; v = tWhh1[r];
  } else if (idx < OFF_W10) {
    int r = idx - OFF_W9; int n = r >> 9, kk = r & 511;
    if (n < 47) v = Wr[n * 512 + kk];
  } else {
    int r = idx - OFF_W10; int n = r >> 9, kk = r & 511;
    if (n < 2) v = Wt[n * 512 + kk];
  }
  w16[idx] = (half_t)v;
}

// fp32 x_r/x_t -> fp16 [t][128][64] (cols 0..46 = x_r, 47..48 = x_t, rest 0)
__global__ __launch_bounds__(256) void conv_x(const float* __restrict__ xr,
                                              const float* __restrict__ xt,
                                              half_t* __restrict__ x16) {
  const int idx = blockIdx.x * 256 + threadIdx.x;
  if (idx >= 512 * 128 * 64) return;
  const int kk = idx & 63;
  const int row = (idx >> 6) & 127;
  const int t = idx >> 13;
  float v = 0.f;
  if (kk < 47) v = xr[(row * 512 + t) * 47 + kk];
  else if (kk < 49) v = xt[(row * 512 + t) * 2 + (kk - 47)];
  x16[idx] = (half_t)v;
}

extern "C" void kernel_launch(void* const* d_in, const int* in_sizes, int n_in,
                              void* d_out, int out_size, void* d_ws,
                              size_t ws_size, hipStream_t stream) {
  const float* xr = (const float*)d_in[0];
  const float* xt = (const float*)d_in[1];
  const float* rWih0 = (const float*)d_in[2];
  const float* rWhh0 = (const float*)d_in[3];
  const float* r_b0 = (const float*)d_in[4];
  const float* rWih1 = (const float*)d_in[5];
  const float* rWhh1 = (const float*)d_in[6];
  const float* r_b1 = (const float*)d_in[7];
  const float* tWih0 = (const float*)d_in[8];
  const float* tWhh0 = (const float*)d_in[9];
  const float* t_b0 = (const float*)d_in[10];
  const float* tWih1 = (const float*)d_in[11];
  const float* tWhh1 = (const float*)d_in[12];
  const float* t_b1 = (const float*)d_in[13];
  const float* Wr = (const float*)d_in[14];
  const float* br = (const float*)d_in[15];
  const float* Wt = (const float*)d_in[16];
  const float* bt = (const float*)d_in[17];

  half_t* w16 = (half_t*)d_ws;
  float* cbase = nullptr;  // c lives in registers
  unsigned* bar = (unsigned*)((char*)d_ws + BAR_BYTE_OFF);
  half_t* x16 = (half_t*)((char*)d_ws + X16_BYTE_OFF);
  float* out = (float*)d_out;
  int use_x16 = (ws_size >= WS_NEED_X16) ? 1 : 0;

  // zero h / ro / counters every call (deterministic)
  (void)hipMemsetAsync((char*)d_ws + STATE_BYTE_OFF, 0, STATE_BYTES, stream);

  conv_w<<<(W_TOTAL + 255) / 256, 256, 0, stream>>>(
      rWih0, rWhh0, rWih1, rWhh1, tWih0, tWhh0, tWih1, tWhh1, Wr, Wt, w16);
  if (use_x16)
    conv_x<<<(512 * 128 * 64) / 256, 256, 0, stream>>>(xr, xt, x16);

  adrnn_persist<<<NBLK, 256, 0, stream>>>(xr, xt, r_b0, r_b1, t_b0, t_b1, br,
                                          bt, w16, cbase, out, bar, x16,
                                          use_x16);
}